// Round 2
// baseline (625.635 us; speedup 1.0000x reference)
//
#include <hip/hip_runtime.h>
#include <climits>

#define HW 262144          // 512*512
#define IW 512
#define RN 725             // rotated canvas side
#define RHW 525625         // 725*725
#define NSEG 256
#define CH_OFF 1536
#define TH_OFF 116736
#define XY_OFF 485376

static __device__ __forceinline__ float loadpix(const float* p, int y, int x, int n) {
    return (y >= 0 && y < n && x >= 0 && x < n) ? p[y * n + x] : 0.0f;
}

// order-preserving f32 <-> u32 map for unsigned atomicMin/Max
static __device__ __forceinline__ unsigned encf(float f) {
    unsigned b = __float_as_uint(f);
    return (b & 0x80000000u) ? ~b : (b | 0x80000000u);
}
static __device__ __forceinline__ float decf(unsigned u) {
    return __uint_as_float((u & 0x80000000u) ? (u ^ 0x80000000u) : ~u);
}

// block-reduce min/max of (g0,g1) and atomically merge into mm_enc[m0],[m1]
static __device__ __forceinline__ void reduce_mm(float g0, float g1, int m0, int m1,
                                                 unsigned* __restrict__ mm_enc) {
    __shared__ float s0lo[256], s0hi[256], s1lo[256], s1hi[256];
    int tid = threadIdx.x;
    s0lo[tid] = g0; s0hi[tid] = g0; s1lo[tid] = g1; s1hi[tid] = g1;
    __syncthreads();
    for (int off = 128; off > 0; off >>= 1) {
        if (tid < off) {
            s0lo[tid] = fminf(s0lo[tid], s0lo[tid + off]);
            s0hi[tid] = fmaxf(s0hi[tid], s0hi[tid + off]);
            s1lo[tid] = fminf(s1lo[tid], s1lo[tid + off]);
            s1hi[tid] = fmaxf(s1hi[tid], s1hi[tid + off]);
        }
        __syncthreads();
    }
    if (tid == 0) {
        atomicMin(&mm_enc[m0 * 2], encf(s0lo[0]));
        atomicMax(&mm_enc[m0 * 2 + 1], encf(s0hi[0]));
        atomicMin(&mm_enc[m1 * 2], encf(s1lo[0]));
        atomicMax(&mm_enc[m1 * 2 + 1], encf(s1hi[0]));
    }
}

// ---- rotate img by +45 into 725x725 canvas (nearest) ----
__global__ void k_rot(const float* __restrict__ img, float* __restrict__ rot) {
    int p = blockIdx.x * blockDim.x + threadIdx.x;
    if (p >= RHW) return;
    int bc = blockIdx.y;                 // b*3+c, 6 images
    int y = p / RN;
    int x = p - y * RN;
    const float cs = 0.7071067811865476f;   // cos45 == sin45 in f32
    float xg = (float)x - 362.0f;           // (725-1)/2
    float yg = (float)y - 362.0f;
    float xi = cs * xg - cs * yg + 255.5f;  // c*xg - s*yg + (W-1)/2
    float yi = cs * xg + cs * yg + 255.5f;  // s*xg + c*yg + (H-1)/2
    int xn = (int)rintf(xi);
    int yn = (int)rintf(yi);
    float v = 0.0f;
    if (xn >= 0 && xn < IW && yn >= 0 && yn < IW)
        v = img[(size_t)bc * HW + yn * IW + xn];
    rot[(size_t)bc * RHW + p] = v;
}

// ---- Scharr on 512x512 image + fused min/max reduce ----
__global__ void k_scharr_img(const float* __restrict__ img, float* __restrict__ g,
                             unsigned* __restrict__ mm_enc) {
    int p = blockIdx.x * blockDim.x + threadIdx.x;
    int bc = blockIdx.y;
    int y = p >> 9, x = p & 511;
    const float* im = img + (size_t)bc * HW;
    float a = loadpix(im, y - 1, x - 1, IW), b = loadpix(im, y - 1, x, IW), c = loadpix(im, y - 1, x + 1, IW);
    float d = loadpix(im, y, x - 1, IW), e = loadpix(im, y, x + 1, IW);
    float f = loadpix(im, y + 1, x - 1, IW), h = loadpix(im, y + 1, x, IW), i = loadpix(im, y + 1, x + 1, IW);
    float g0 = -3.f * a + 3.f * c + 10.f * d + 10.f * e - 3.f * f + 3.f * i;
    float g1 = -3.f * a + 10.f * b - 3.f * c + 3.f * f + 10.f * h + 3.f * i;
    g[((size_t)bc * 2 + 0) * HW + p] = g0;
    g[((size_t)bc * 2 + 1) * HW + p] = g1;
    reduce_mm(g0, g1, bc * 2 + 0, bc * 2 + 1, mm_enc);
}

// ---- fused rotate-back(-45) + Scharr of rot, cropped [105:617], + min/max reduce ----
__global__ void k_grc(const float* __restrict__ rot, float* __restrict__ grc,
                      unsigned* __restrict__ mm_enc) {
    int p = blockIdx.x * blockDim.x + threadIdx.x;
    int bc = blockIdx.y;
    int y = p >> 9, x = p & 511;
    const float cs = 0.7071067811865476f;  // cos(-45); sin(-45) = -cs
    float xg = (float)(x + 105) - 512.5f;  // (1026-1)/2
    float yg = (float)(y + 105) - 512.5f;
    float t1 = cs * xg, t2 = cs * yg;
    float xi = (t1 + t2) + 362.0f;
    float yi = (-t1 + t2) + 362.0f;
    int xn = (int)rintf(xi);
    int yn = (int)rintf(yi);
    float g0 = 0.f, g1 = 0.f;
    if (xn >= 0 && xn < RN && yn >= 0 && yn < RN) {
        const float* im = rot + (size_t)bc * RHW;
        float a = loadpix(im, yn - 1, xn - 1, RN), b = loadpix(im, yn - 1, xn, RN), c = loadpix(im, yn - 1, xn + 1, RN);
        float d = loadpix(im, yn, xn - 1, RN), e = loadpix(im, yn, xn + 1, RN);
        float f = loadpix(im, yn + 1, xn - 1, RN), h = loadpix(im, yn + 1, xn, RN), i = loadpix(im, yn + 1, xn + 1, RN);
        g0 = -3.f * a + 3.f * c + 10.f * d + 10.f * e - 3.f * f + 3.f * i;
        g1 = -3.f * a + 10.f * b - 3.f * c + 3.f * f + 10.f * h + 3.f * i;
    }
    grc[((size_t)bc * 2 + 0) * HW + p] = g0;
    grc[((size_t)bc * 2 + 1) * HW + p] = g1;
    reduce_mm(g0, g1, 12 + bc * 2 + 0, 12 + bc * 2 + 1, mm_enc);
}

// ---- init bbox arrays + encoded minmax slots ----
__global__ void k_init(int* __restrict__ bb, unsigned* __restrict__ mm_enc) {
    int i = blockIdx.x * blockDim.x + threadIdx.x;  // 1536 total
    bb[i] = INT_MAX;            // xmin
    bb[1536 + i] = INT_MIN;     // xmax
    bb[3072 + i] = INT_MAX;     // ymin
    bb[4608 + i] = INT_MIN;     // ymax
    if (blockIdx.x == 0 && threadIdx.x < 96)
        mm_enc[threadIdx.x] = (threadIdx.x & 1) ? 0u : 0xFFFFFFFFu;  // [min=UINT_MAX, max=0]
}

// ---- region sizes + bbox: LDS hist + LDS min/max, merged with global atomics ----
__global__ void k_region(const int* __restrict__ lab, float* __restrict__ rs_out, int* __restrict__ bb) {
    __shared__ unsigned cnt[NSEG];
    __shared__ int sxmin[NSEG], sxmax[NSEG], symin[NSEG], symax[NSEG];
    int big = blockIdx.y;  // b*3+g
    for (int i = threadIdx.x; i < NSEG; i += blockDim.x) {
        cnt[i] = 0; sxmin[i] = INT_MAX; sxmax[i] = INT_MIN; symin[i] = INT_MAX; symax[i] = INT_MIN;
    }
    __syncthreads();
    int stride = blockDim.x * gridDim.x;
    const int* lp = lab + (size_t)big * HW;
    for (int p = blockIdx.x * blockDim.x + threadIdx.x; p < HW; p += stride) {
        int l = lp[p] & 255;
        int y = p >> 9, x = p & 511;
        atomicAdd(&cnt[l], 1u);
        atomicMin(&sxmin[l], x); atomicMax(&sxmax[l], x);
        atomicMin(&symin[l], y); atomicMax(&symax[l], y);
    }
    __syncthreads();
    for (int i = threadIdx.x; i < NSEG; i += blockDim.x) {
        if (cnt[i]) atomicAdd(&rs_out[big * NSEG + i], (float)cnt[i]);
        if (sxmin[i] != INT_MAX) {
            atomicMin(&bb[big * NSEG + i], sxmin[i]);
            atomicMax(&bb[1536 + big * NSEG + i], sxmax[i]);
            atomicMin(&bb[3072 + big * NSEG + i], symin[i]);
            atomicMax(&bb[4608 + big * NSEG + i], symax[i]);
        }
    }
}

// ---- color histogram: per (b,g,c), 6400-bin LDS hist ----
__global__ void k_chist(const float* __restrict__ img, const int* __restrict__ lab, float* __restrict__ ch_out) {
    __shared__ unsigned cnt[NSEG * 25];
    int gy = blockIdx.y;       // (b*3+g)*3 + c
    int c = gy % 3;
    int bg = gy / 3;           // b*3+g
    int b = bg / 3;
    for (int i = threadIdx.x; i < NSEG * 25; i += blockDim.x) cnt[i] = 0;
    __syncthreads();
    const float* ip = img + ((size_t)b * 3 + c) * HW;
    const int* lp = lab + (size_t)bg * HW;
    int stride = blockDim.x * gridDim.x;
    for (int p = blockIdx.x * blockDim.x + threadIdx.x; p < HW; p += stride) {
        int l = lp[p] & 255;
        float v = ip[p];
        int bin = (int)((float)l * 25.0f + v * 24.0f);  // matches ref f32 op order
        bin = min(max(bin, 0), NSEG * 25 - 1);
        atomicAdd(&cnt[bin], 1u);
    }
    __syncthreads();
    for (int i = threadIdx.x; i < NSEG * 25; i += blockDim.x) {
        unsigned n = cnt[i];
        if (n) {
            int s = i / 25, cb = i - s * 25;
            atomicAdd(&ch_out[((size_t)(bg * NSEG + s) * 3 + c) * 25 + cb], (float)n);
        }
    }
}

// ---- texture histogram: per (b,c,t), 3 label maps x 2560-bin LDS hists ----
__global__ void k_thist(const float* __restrict__ maps, const int* __restrict__ lab,
                        const unsigned* __restrict__ mm_enc, float* __restrict__ th_out) {
    __shared__ unsigned cnt[3 * 2560];  // 30720 B
    int gy = blockIdx.y;    // bc*8 + t
    int t = gy & 7;
    int bc = gy >> 3;       // b*3+c
    int b = bc / 3;
    int c = bc - b * 3;
    int d = t & 1;
    int pos = (((t >> 1) & 1) == 0);
    int base = t >> 2;      // 0: g maps, 1: grc maps
    int m = base * 12 + bc * 2 + d;
    for (int i = threadIdx.x; i < 3 * 2560; i += blockDim.x) cnt[i] = 0;
    __syncthreads();
    float mn = decf(mm_enc[m * 2]), mx = decf(mm_enc[m * 2 + 1]);
    float hmin = pos ? fmaxf(mn, 0.f) : fminf(mn, 0.f);
    float hmax = pos ? fmaxf(mx, 0.f) : fminf(mx, 0.f);
    float den = hmax - hmin;
    const float* src = maps + (size_t)m * HW;
    const int* l0 = lab + (size_t)(b * 3 + 0) * HW;
    const int* l1 = lab + (size_t)(b * 3 + 1) * HW;
    const int* l2 = lab + (size_t)(b * 3 + 2) * HW;
    int stride = blockDim.x * gridDim.x;
    for (int p = blockIdx.x * blockDim.x + threadIdx.x; p < HW; p += stride) {
        float v = src[p];
        float vc = pos ? fmaxf(v, 0.f) : fminf(v, 0.f);
        float tn = (vc - hmin) / den;        // division, matching ref
        float t9 = tn * 9.0f;
        int la = l0[p] & 255, lb = l1[p] & 255, lc = l2[p] & 255;
        int b0 = (int)((float)la * 10.0f + t9);
        int b1 = (int)((float)lb * 10.0f + t9);
        int b2 = (int)((float)lc * 10.0f + t9);
        b0 = min(max(b0, 0), 2559); b1 = min(max(b1, 0), 2559); b2 = min(max(b2, 0), 2559);
        atomicAdd(&cnt[b0], 1u);
        atomicAdd(&cnt[2560 + b1], 1u);
        atomicAdd(&cnt[5120 + b2], 1u);
    }
    __syncthreads();
    for (int i = threadIdx.x; i < 3 * 2560; i += blockDim.x) {
        unsigned n = cnt[i];
        if (n) {
            int gi = i / 2560;
            int r = i - gi * 2560;
            int s = r / 10, tb = r - s * 10;
            // th layout: (B,I,G,S,C,8,10)
            size_t idx = ((size_t)((b * 3 + gi) * NSEG + s) * 3 + c) * 80 + t * 10 + tb;
            atomicAdd(&th_out[idx], (float)n);
        }
    }
}

// ---- normalize ch/th and write xywh ----
__global__ void k_final(float* __restrict__ out, const int* __restrict__ bb) {
    int seg = blockIdx.x;   // big*256 + s, 1536 total
    float rs = out[seg];
    float cd = 3.0f * rs;
    float td = 24.0f * rs;
    float* ch = out + CH_OFF + (size_t)seg * 75;
    float* th = out + TH_OFF + (size_t)seg * 240;
    for (int i = threadIdx.x; i < 75; i += blockDim.x) ch[i] = ch[i] / cd;
    for (int i = threadIdx.x; i < 240; i += blockDim.x) th[i] = th[i] / td;
    if (threadIdx.x == 0) {
        int xmin, xmax, ymin, ymax;
        if (rs > 0.f) {
            xmin = bb[seg]; xmax = bb[1536 + seg];
            ymin = bb[3072 + seg]; ymax = bb[4608 + seg];
        } else {
            xmin = IW; ymin = IW; xmax = 0; ymax = 0;
        }
        float* xy = out + XY_OFF + (size_t)seg * 4;
        xy[0] = (float)xmin; xy[1] = (float)ymin;
        xy[2] = (float)(xmax - xmin); xy[3] = (float)(ymax - ymin);
    }
}

extern "C" void kernel_launch(void* const* d_in, const int* in_sizes, int n_in,
                              void* d_out, int out_size, void* d_ws, size_t ws_size,
                              hipStream_t stream) {
    const float* img = (const float*)d_in[0];
    const int* lab = (const int*)d_in[1];
    float* out = (float*)d_out;

    float* ws = (float*)d_ws;
    float* rot = ws;                              // 6*725*725 = 3,153,750 f
    float* gmaps = rot + (size_t)6 * RHW;         // 12 maps * 262144
    float* grcmaps = gmaps + (size_t)12 * HW;     // 12 maps (contiguous after g)
    unsigned* mm_enc = (unsigned*)(grcmaps + (size_t)12 * HW);  // 96 u32 (48 min/max pairs)
    int* bb = (int*)(mm_enc + 96);                // 4*1536 ints

    hipMemsetAsync(d_out, 0, (size_t)out_size * sizeof(float), stream);
    hipLaunchKernelGGL(k_init, dim3(6), dim3(256), 0, stream, bb, mm_enc);
    hipLaunchKernelGGL(k_rot, dim3((RHW + 255) / 256, 6), dim3(256), 0, stream, img, rot);
    hipLaunchKernelGGL(k_scharr_img, dim3(HW / 256, 6), dim3(256), 0, stream, img, gmaps, mm_enc);
    hipLaunchKernelGGL(k_grc, dim3(HW / 256, 6), dim3(256), 0, stream, rot, grcmaps, mm_enc);
    hipLaunchKernelGGL(k_region, dim3(32, 6), dim3(256), 0, stream, lab, out, bb);
    hipLaunchKernelGGL(k_chist, dim3(16, 18), dim3(256), 0, stream, img, lab, out + CH_OFF);
    hipLaunchKernelGGL(k_thist, dim3(8, 48), dim3(256), 0, stream, gmaps, lab, mm_enc, out + TH_OFF);
    hipLaunchKernelGGL(k_final, dim3(1536), dim3(64), 0, stream, out, bb);
}

// Round 3
// 247.603 us; speedup vs baseline: 2.5268x; 2.5268x over previous
//
#include <hip/hip_runtime.h>
#include <climits>

#define HW 262144          // 512*512
#define IW 512
#define RN 725             // rotated canvas side
#define RHW 525625         // 725*725
#define NSEG 256
#define CH_OFF 1536
#define TH_OFF 116736
#define XY_OFF 485376
#define NBLK 1024          // blocks per image in scharr/grc

static __device__ __forceinline__ float loadpix(const float* p, int y, int x, int n) {
    return (y >= 0 && y < n && x >= 0 && x < n) ? p[y * n + x] : 0.0f;
}

// block-reduce min/max of (g0,g1); write per-block partials (NO atomics)
static __device__ __forceinline__ void reduce_mm(float g0, float g1, int m0, int m1,
                                                 float* __restrict__ pmin, float* __restrict__ pmax) {
    __shared__ float s0lo[256], s0hi[256], s1lo[256], s1hi[256];
    int tid = threadIdx.x;
    s0lo[tid] = g0; s0hi[tid] = g0; s1lo[tid] = g1; s1hi[tid] = g1;
    __syncthreads();
    for (int off = 128; off > 0; off >>= 1) {
        if (tid < off) {
            s0lo[tid] = fminf(s0lo[tid], s0lo[tid + off]);
            s0hi[tid] = fmaxf(s0hi[tid], s0hi[tid + off]);
            s1lo[tid] = fminf(s1lo[tid], s1lo[tid + off]);
            s1hi[tid] = fmaxf(s1hi[tid], s1hi[tid + off]);
        }
        __syncthreads();
    }
    if (tid == 0) {
        int bx = blockIdx.x;
        pmin[m0 * NBLK + bx] = s0lo[0];
        pmax[m0 * NBLK + bx] = s0hi[0];
        pmin[m1 * NBLK + bx] = s1lo[0];
        pmax[m1 * NBLK + bx] = s1hi[0];
    }
}

// ---- rotate img by +45 into 725x725 canvas (nearest) ----
__global__ void k_rot(const float* __restrict__ img, float* __restrict__ rot) {
    int p = blockIdx.x * blockDim.x + threadIdx.x;
    if (p >= RHW) return;
    int bc = blockIdx.y;                 // b*3+c, 6 images
    int y = p / RN;
    int x = p - y * RN;
    const float cs = 0.7071067811865476f;   // cos45 == sin45 in f32
    float xg = (float)x - 362.0f;           // (725-1)/2
    float yg = (float)y - 362.0f;
    float xi = cs * xg - cs * yg + 255.5f;  // c*xg - s*yg + (W-1)/2
    float yi = cs * xg + cs * yg + 255.5f;  // s*xg + c*yg + (H-1)/2
    int xn = (int)rintf(xi);
    int yn = (int)rintf(yi);
    float v = 0.0f;
    if (xn >= 0 && xn < IW && yn >= 0 && yn < IW)
        v = img[(size_t)bc * HW + yn * IW + xn];
    rot[(size_t)bc * RHW + p] = v;
}

// ---- Scharr on 512x512 image + per-block min/max partials ----
__global__ void k_scharr_img(const float* __restrict__ img, float* __restrict__ g,
                             float* __restrict__ pmin, float* __restrict__ pmax) {
    int p = blockIdx.x * blockDim.x + threadIdx.x;
    int bc = blockIdx.y;
    int y = p >> 9, x = p & 511;
    const float* im = img + (size_t)bc * HW;
    float a = loadpix(im, y - 1, x - 1, IW), b = loadpix(im, y - 1, x, IW), c = loadpix(im, y - 1, x + 1, IW);
    float d = loadpix(im, y, x - 1, IW), e = loadpix(im, y, x + 1, IW);
    float f = loadpix(im, y + 1, x - 1, IW), h = loadpix(im, y + 1, x, IW), i = loadpix(im, y + 1, x + 1, IW);
    float g0 = -3.f * a + 3.f * c + 10.f * d + 10.f * e - 3.f * f + 3.f * i;
    float g1 = -3.f * a + 10.f * b - 3.f * c + 3.f * f + 10.f * h + 3.f * i;
    g[((size_t)bc * 2 + 0) * HW + p] = g0;
    g[((size_t)bc * 2 + 1) * HW + p] = g1;
    reduce_mm(g0, g1, bc * 2 + 0, bc * 2 + 1, pmin, pmax);
}

// ---- fused rotate-back(-45) + Scharr of rot, cropped [105:617], + partials ----
__global__ void k_grc(const float* __restrict__ rot, float* __restrict__ grc,
                      float* __restrict__ pmin, float* __restrict__ pmax) {
    int p = blockIdx.x * blockDim.x + threadIdx.x;
    int bc = blockIdx.y;
    int y = p >> 9, x = p & 511;
    const float cs = 0.7071067811865476f;  // cos(-45); sin(-45) = -cs
    float xg = (float)(x + 105) - 512.5f;  // (1026-1)/2
    float yg = (float)(y + 105) - 512.5f;
    float t1 = cs * xg, t2 = cs * yg;
    float xi = (t1 + t2) + 362.0f;
    float yi = (-t1 + t2) + 362.0f;
    int xn = (int)rintf(xi);
    int yn = (int)rintf(yi);
    float g0 = 0.f, g1 = 0.f;
    if (xn >= 0 && xn < RN && yn >= 0 && yn < RN) {
        const float* im = rot + (size_t)bc * RHW;
        float a = loadpix(im, yn - 1, xn - 1, RN), b = loadpix(im, yn - 1, xn, RN), c = loadpix(im, yn - 1, xn + 1, RN);
        float d = loadpix(im, yn, xn - 1, RN), e = loadpix(im, yn, xn + 1, RN);
        float f = loadpix(im, yn + 1, xn - 1, RN), h = loadpix(im, yn + 1, xn, RN), i = loadpix(im, yn + 1, xn + 1, RN);
        g0 = -3.f * a + 3.f * c + 10.f * d + 10.f * e - 3.f * f + 3.f * i;
        g1 = -3.f * a + 10.f * b - 3.f * c + 3.f * f + 10.f * h + 3.f * i;
    }
    grc[((size_t)bc * 2 + 0) * HW + p] = g0;
    grc[((size_t)bc * 2 + 1) * HW + p] = g1;
    reduce_mm(g0, g1, 12 + bc * 2 + 0, 12 + bc * 2 + 1, pmin, pmax);
}

// ---- stage-2: reduce 1024 partials per map -> mm[m*2], mm[m*2+1] ----
__global__ void k_mmreduce(const float* __restrict__ pmin, const float* __restrict__ pmax,
                           float* __restrict__ mm) {
    int m = blockIdx.x;
    int tid = threadIdx.x;
    float lo = 3.4e38f, hi = -3.4e38f;
    for (int i = tid; i < NBLK; i += 256) {
        lo = fminf(lo, pmin[m * NBLK + i]);
        hi = fmaxf(hi, pmax[m * NBLK + i]);
    }
    __shared__ float slo[256], shi[256];
    slo[tid] = lo; shi[tid] = hi;
    __syncthreads();
    for (int off = 128; off > 0; off >>= 1) {
        if (tid < off) {
            slo[tid] = fminf(slo[tid], slo[tid + off]);
            shi[tid] = fmaxf(shi[tid], shi[tid + off]);
        }
        __syncthreads();
    }
    if (tid == 0) { mm[m * 2] = slo[0]; mm[m * 2 + 1] = shi[0]; }
}

__global__ void k_init_bb(int* __restrict__ bb) {
    int i = blockIdx.x * blockDim.x + threadIdx.x;  // 1536 total
    bb[i] = INT_MAX;            // xmin
    bb[1536 + i] = INT_MIN;     // xmax
    bb[3072 + i] = INT_MAX;     // ymin
    bb[4608 + i] = INT_MIN;     // ymax
}

// ---- region sizes + bbox: LDS hist + LDS min/max, merged with global atomics ----
__global__ void k_region(const int* __restrict__ lab, float* __restrict__ rs_out, int* __restrict__ bb) {
    __shared__ unsigned cnt[NSEG];
    __shared__ int sxmin[NSEG], sxmax[NSEG], symin[NSEG], symax[NSEG];
    int big = blockIdx.y;  // b*3+g
    for (int i = threadIdx.x; i < NSEG; i += blockDim.x) {
        cnt[i] = 0; sxmin[i] = INT_MAX; sxmax[i] = INT_MIN; symin[i] = INT_MAX; symax[i] = INT_MIN;
    }
    __syncthreads();
    int stride = blockDim.x * gridDim.x;
    const int* lp = lab + (size_t)big * HW;
    for (int p = blockIdx.x * blockDim.x + threadIdx.x; p < HW; p += stride) {
        int l = lp[p] & 255;
        int y = p >> 9, x = p & 511;
        atomicAdd(&cnt[l], 1u);
        atomicMin(&sxmin[l], x); atomicMax(&sxmax[l], x);
        atomicMin(&symin[l], y); atomicMax(&symax[l], y);
    }
    __syncthreads();
    for (int i = threadIdx.x; i < NSEG; i += blockDim.x) {
        if (cnt[i]) atomicAdd(&rs_out[big * NSEG + i], (float)cnt[i]);
        if (sxmin[i] != INT_MAX) {
            atomicMin(&bb[big * NSEG + i], sxmin[i]);
            atomicMax(&bb[1536 + big * NSEG + i], sxmax[i]);
            atomicMin(&bb[3072 + big * NSEG + i], symin[i]);
            atomicMax(&bb[4608 + big * NSEG + i], symax[i]);
        }
    }
}

// ---- color histogram: per (b,g,c), 6400-bin LDS hist ----
__global__ void k_chist(const float* __restrict__ img, const int* __restrict__ lab, float* __restrict__ ch_out) {
    __shared__ unsigned cnt[NSEG * 25];
    int gy = blockIdx.y;       // (b*3+g)*3 + c
    int c = gy % 3;
    int bg = gy / 3;           // b*3+g
    int b = bg / 3;
    for (int i = threadIdx.x; i < NSEG * 25; i += blockDim.x) cnt[i] = 0;
    __syncthreads();
    const float* ip = img + ((size_t)b * 3 + c) * HW;
    const int* lp = lab + (size_t)bg * HW;
    int stride = blockDim.x * gridDim.x;
    for (int p = blockIdx.x * blockDim.x + threadIdx.x; p < HW; p += stride) {
        int l = lp[p] & 255;
        float v = ip[p];
        int bin = (int)((float)l * 25.0f + v * 24.0f);  // matches ref f32 op order
        bin = min(max(bin, 0), NSEG * 25 - 1);
        atomicAdd(&cnt[bin], 1u);
    }
    __syncthreads();
    for (int i = threadIdx.x; i < NSEG * 25; i += blockDim.x) {
        unsigned n = cnt[i];
        if (n) {
            int s = i / 25, cb = i - s * 25;
            atomicAdd(&ch_out[((size_t)(bg * NSEG + s) * 3 + c) * 25 + cb], (float)n);
        }
    }
}

// ---- texture histogram: per (b,c,t), 3 label maps x 2560-bin LDS hists ----
__global__ void k_thist(const float* __restrict__ maps, const int* __restrict__ lab,
                        const float* __restrict__ mm, float* __restrict__ th_out) {
    __shared__ unsigned cnt[3 * 2560];  // 30720 B
    int gy = blockIdx.y;    // bc*8 + t
    int t = gy & 7;
    int bc = gy >> 3;       // b*3+c
    int b = bc / 3;
    int c = bc - b * 3;
    int d = t & 1;
    int pos = (((t >> 1) & 1) == 0);
    int base = t >> 2;      // 0: g maps, 1: grc maps
    int m = base * 12 + bc * 2 + d;
    for (int i = threadIdx.x; i < 3 * 2560; i += blockDim.x) cnt[i] = 0;
    __syncthreads();
    float mn = mm[m * 2], mx = mm[m * 2 + 1];
    float hmin = pos ? fmaxf(mn, 0.f) : fminf(mn, 0.f);
    float hmax = pos ? fmaxf(mx, 0.f) : fminf(mx, 0.f);
    float den = hmax - hmin;
    const float* src = maps + (size_t)m * HW;
    const int* l0 = lab + (size_t)(b * 3 + 0) * HW;
    const int* l1 = lab + (size_t)(b * 3 + 1) * HW;
    const int* l2 = lab + (size_t)(b * 3 + 2) * HW;
    int stride = blockDim.x * gridDim.x;
    for (int p = blockIdx.x * blockDim.x + threadIdx.x; p < HW; p += stride) {
        float v = src[p];
        float vc = pos ? fmaxf(v, 0.f) : fminf(v, 0.f);
        float tn = (vc - hmin) / den;        // division, matching ref
        float t9 = tn * 9.0f;
        int la = l0[p] & 255, lb = l1[p] & 255, lc = l2[p] & 255;
        int b0 = (int)((float)la * 10.0f + t9);
        int b1 = (int)((float)lb * 10.0f + t9);
        int b2 = (int)((float)lc * 10.0f + t9);
        b0 = min(max(b0, 0), 2559); b1 = min(max(b1, 0), 2559); b2 = min(max(b2, 0), 2559);
        atomicAdd(&cnt[b0], 1u);
        atomicAdd(&cnt[2560 + b1], 1u);
        atomicAdd(&cnt[5120 + b2], 1u);
    }
    __syncthreads();
    for (int i = threadIdx.x; i < 3 * 2560; i += blockDim.x) {
        unsigned n = cnt[i];
        if (n) {
            int gi = i / 2560;
            int r = i - gi * 2560;
            int s = r / 10, tb = r - s * 10;
            // th layout: (B,I,G,S,C,8,10)
            size_t idx = ((size_t)((b * 3 + gi) * NSEG + s) * 3 + c) * 80 + t * 10 + tb;
            atomicAdd(&th_out[idx], (float)n);
        }
    }
}

// ---- normalize ch/th and write xywh ----
__global__ void k_final(float* __restrict__ out, const int* __restrict__ bb) {
    int seg = blockIdx.x;   // big*256 + s, 1536 total
    float rs = out[seg];
    float cd = 3.0f * rs;
    float td = 24.0f * rs;
    float* ch = out + CH_OFF + (size_t)seg * 75;
    float* th = out + TH_OFF + (size_t)seg * 240;
    for (int i = threadIdx.x; i < 75; i += blockDim.x) ch[i] = ch[i] / cd;
    for (int i = threadIdx.x; i < 240; i += blockDim.x) th[i] = th[i] / td;
    if (threadIdx.x == 0) {
        int xmin, xmax, ymin, ymax;
        if (rs > 0.f) {
            xmin = bb[seg]; xmax = bb[1536 + seg];
            ymin = bb[3072 + seg]; ymax = bb[4608 + seg];
        } else {
            xmin = IW; ymin = IW; xmax = 0; ymax = 0;
        }
        float* xy = out + XY_OFF + (size_t)seg * 4;
        xy[0] = (float)xmin; xy[1] = (float)ymin;
        xy[2] = (float)(xmax - xmin); xy[3] = (float)(ymax - ymin);
    }
}

extern "C" void kernel_launch(void* const* d_in, const int* in_sizes, int n_in,
                              void* d_out, int out_size, void* d_ws, size_t ws_size,
                              hipStream_t stream) {
    const float* img = (const float*)d_in[0];
    const int* lab = (const int*)d_in[1];
    float* out = (float*)d_out;

    float* ws = (float*)d_ws;
    float* rot = ws;                              // 6*725*725 = 3,153,750 f
    float* gmaps = rot + (size_t)6 * RHW;         // 12 maps * 262144
    float* grcmaps = gmaps + (size_t)12 * HW;     // 12 maps (contiguous after g)
    float* pmin = grcmaps + (size_t)12 * HW;      // 24*1024
    float* pmax = pmin + 24 * NBLK;               // 24*1024
    float* mm = pmax + 24 * NBLK;                 // 48 floats
    int* bb = (int*)(mm + 48);                    // 4*1536 ints

    hipMemsetAsync(d_out, 0, (size_t)out_size * sizeof(float), stream);
    hipLaunchKernelGGL(k_init_bb, dim3(6), dim3(256), 0, stream, bb);
    hipLaunchKernelGGL(k_rot, dim3((RHW + 255) / 256, 6), dim3(256), 0, stream, img, rot);
    hipLaunchKernelGGL(k_scharr_img, dim3(NBLK, 6), dim3(256), 0, stream, img, gmaps, pmin, pmax);
    hipLaunchKernelGGL(k_grc, dim3(NBLK, 6), dim3(256), 0, stream, rot, grcmaps, pmin, pmax);
    hipLaunchKernelGGL(k_mmreduce, dim3(24), dim3(256), 0, stream, pmin, pmax, mm);
    hipLaunchKernelGGL(k_region, dim3(32, 6), dim3(256), 0, stream, lab, out, bb);
    hipLaunchKernelGGL(k_chist, dim3(16, 18), dim3(256), 0, stream, img, lab, out + CH_OFF);
    hipLaunchKernelGGL(k_thist, dim3(8, 48), dim3(256), 0, stream, gmaps, lab, mm, out + TH_OFF);
    hipLaunchKernelGGL(k_final, dim3(1536), dim3(64), 0, stream, out, bb);
}

// Round 4
// 224.585 us; speedup vs baseline: 2.7857x; 1.1025x over previous
//
#include <hip/hip_runtime.h>
#include <climits>

#define HW 262144          // 512*512
#define IW 512
#define RN 725             // rotated canvas side
#define RHW 525625         // 725*725
#define ROT_PAD 3153752    // 6*RHW rounded up so following buffers stay 16B-aligned
#define NSEG 256
#define CH_OFF 1536
#define TH_OFF 116736
#define XY_OFF 485376
#define NBLK 1024          // blocks per image in scharr/grc
#define THP 12             // pixel splits in k_thist

static __device__ __forceinline__ float loadpix(const float* p, int y, int x, int n) {
    return (y >= 0 && y < n && x >= 0 && x < n) ? p[y * n + x] : 0.0f;
}

// block-reduce min/max of (g0,g1); write per-block partials (NO atomics)
static __device__ __forceinline__ void reduce_mm(float g0, float g1, int m0, int m1,
                                                 float* __restrict__ pmin, float* __restrict__ pmax) {
    __shared__ float s0lo[256], s0hi[256], s1lo[256], s1hi[256];
    int tid = threadIdx.x;
    s0lo[tid] = g0; s0hi[tid] = g0; s1lo[tid] = g1; s1hi[tid] = g1;
    __syncthreads();
    for (int off = 128; off > 0; off >>= 1) {
        if (tid < off) {
            s0lo[tid] = fminf(s0lo[tid], s0lo[tid + off]);
            s0hi[tid] = fmaxf(s0hi[tid], s0hi[tid + off]);
            s1lo[tid] = fminf(s1lo[tid], s1lo[tid + off]);
            s1hi[tid] = fmaxf(s1hi[tid], s1hi[tid + off]);
        }
        __syncthreads();
    }
    if (tid == 0) {
        int bx = blockIdx.x;
        pmin[m0 * NBLK + bx] = s0lo[0];
        pmax[m0 * NBLK + bx] = s0hi[0];
        pmin[m1 * NBLK + bx] = s1lo[0];
        pmax[m1 * NBLK + bx] = s1hi[0];
    }
}

// ---- rotate img by +45 into 725x725 canvas (nearest) ----
__global__ void k_rot(const float* __restrict__ img, float* __restrict__ rot) {
    int p = blockIdx.x * blockDim.x + threadIdx.x;
    if (p >= RHW) return;
    int bc = blockIdx.y;                 // b*3+c, 6 images
    int y = p / RN;
    int x = p - y * RN;
    const float cs = 0.7071067811865476f;   // cos45 == sin45 in f32
    float xg = (float)x - 362.0f;           // (725-1)/2
    float yg = (float)y - 362.0f;
    float xi = cs * xg - cs * yg + 255.5f;  // c*xg - s*yg + (W-1)/2
    float yi = cs * xg + cs * yg + 255.5f;  // s*xg + c*yg + (H-1)/2
    int xn = (int)rintf(xi);
    int yn = (int)rintf(yi);
    float v = 0.0f;
    if (xn >= 0 && xn < IW && yn >= 0 && yn < IW)
        v = img[(size_t)bc * HW + yn * IW + xn];
    rot[(size_t)bc * RHW + p] = v;
}

// ---- Scharr on 512x512 image + per-block min/max partials ----
__global__ void k_scharr_img(const float* __restrict__ img, float* __restrict__ g,
                             float* __restrict__ pmin, float* __restrict__ pmax) {
    int p = blockIdx.x * blockDim.x + threadIdx.x;
    int bc = blockIdx.y;
    int y = p >> 9, x = p & 511;
    const float* im = img + (size_t)bc * HW;
    float a = loadpix(im, y - 1, x - 1, IW), b = loadpix(im, y - 1, x, IW), c = loadpix(im, y - 1, x + 1, IW);
    float d = loadpix(im, y, x - 1, IW), e = loadpix(im, y, x + 1, IW);
    float f = loadpix(im, y + 1, x - 1, IW), h = loadpix(im, y + 1, x, IW), i = loadpix(im, y + 1, x + 1, IW);
    float g0 = -3.f * a + 3.f * c + 10.f * d + 10.f * e - 3.f * f + 3.f * i;
    float g1 = -3.f * a + 10.f * b - 3.f * c + 3.f * f + 10.f * h + 3.f * i;
    g[((size_t)bc * 2 + 0) * HW + p] = g0;
    g[((size_t)bc * 2 + 1) * HW + p] = g1;
    reduce_mm(g0, g1, bc * 2 + 0, bc * 2 + 1, pmin, pmax);
}

// ---- fused rotate-back(-45) + Scharr of rot, cropped [105:617], + partials ----
__global__ void k_grc(const float* __restrict__ rot, float* __restrict__ grc,
                      float* __restrict__ pmin, float* __restrict__ pmax) {
    int p = blockIdx.x * blockDim.x + threadIdx.x;
    int bc = blockIdx.y;
    int y = p >> 9, x = p & 511;
    const float cs = 0.7071067811865476f;  // cos(-45); sin(-45) = -cs
    float xg = (float)(x + 105) - 512.5f;  // (1026-1)/2
    float yg = (float)(y + 105) - 512.5f;
    float t1 = cs * xg, t2 = cs * yg;
    float xi = (t1 + t2) + 362.0f;
    float yi = (-t1 + t2) + 362.0f;
    int xn = (int)rintf(xi);
    int yn = (int)rintf(yi);
    float g0 = 0.f, g1 = 0.f;
    if (xn >= 0 && xn < RN && yn >= 0 && yn < RN) {
        const float* im = rot + (size_t)bc * RHW;
        float a = loadpix(im, yn - 1, xn - 1, RN), b = loadpix(im, yn - 1, xn, RN), c = loadpix(im, yn - 1, xn + 1, RN);
        float d = loadpix(im, yn, xn - 1, RN), e = loadpix(im, yn, xn + 1, RN);
        float f = loadpix(im, yn + 1, xn - 1, RN), h = loadpix(im, yn + 1, xn, RN), i = loadpix(im, yn + 1, xn + 1, RN);
        g0 = -3.f * a + 3.f * c + 10.f * d + 10.f * e - 3.f * f + 3.f * i;
        g1 = -3.f * a + 10.f * b - 3.f * c + 3.f * f + 10.f * h + 3.f * i;
    }
    grc[((size_t)bc * 2 + 0) * HW + p] = g0;
    grc[((size_t)bc * 2 + 1) * HW + p] = g1;
    reduce_mm(g0, g1, 12 + bc * 2 + 0, 12 + bc * 2 + 1, pmin, pmax);
}

// ---- stage-2: reduce 1024 partials per map -> mm[m*2], mm[m*2+1] ----
__global__ void k_mmreduce(const float* __restrict__ pmin, const float* __restrict__ pmax,
                           float* __restrict__ mm) {
    int m = blockIdx.x;
    int tid = threadIdx.x;
    float lo = 3.4e38f, hi = -3.4e38f;
    for (int i = tid; i < NBLK; i += 256) {
        lo = fminf(lo, pmin[m * NBLK + i]);
        hi = fmaxf(hi, pmax[m * NBLK + i]);
    }
    __shared__ float slo[256], shi[256];
    slo[tid] = lo; shi[tid] = hi;
    __syncthreads();
    for (int off = 128; off > 0; off >>= 1) {
        if (tid < off) {
            slo[tid] = fminf(slo[tid], slo[tid + off]);
            shi[tid] = fmaxf(shi[tid], shi[tid + off]);
        }
        __syncthreads();
    }
    if (tid == 0) { mm[m * 2] = slo[0]; mm[m * 2 + 1] = shi[0]; }
}

__global__ void k_init_bb(int* __restrict__ bb) {
    int i = blockIdx.x * blockDim.x + threadIdx.x;  // 1536 total
    bb[i] = INT_MAX;            // xmin
    bb[1536 + i] = INT_MIN;     // xmax
    bb[3072 + i] = INT_MAX;     // ymin
    bb[4608 + i] = INT_MIN;     // ymax
}

// ---- region sizes + bbox: LDS hist + LDS min/max, merged with global atomics ----
__global__ void k_region(const int* __restrict__ lab, float* __restrict__ rs_out, int* __restrict__ bb) {
    __shared__ unsigned cnt[NSEG];
    __shared__ int sxmin[NSEG], sxmax[NSEG], symin[NSEG], symax[NSEG];
    int big = blockIdx.y;  // b*3+g
    for (int i = threadIdx.x; i < NSEG; i += blockDim.x) {
        cnt[i] = 0; sxmin[i] = INT_MAX; sxmax[i] = INT_MIN; symin[i] = INT_MAX; symax[i] = INT_MIN;
    }
    __syncthreads();
    const int4* lp = (const int4*)(lab + (size_t)big * HW);
    int stride = blockDim.x * gridDim.x;
    for (int i = blockIdx.x * blockDim.x + threadIdx.x; i < HW / 4; i += stride) {
        int4 l4 = lp[i];
        int p = i << 2;
        int y = p >> 9, x = p & 511;
        int l0 = l4.x & 255, l1 = l4.y & 255, l2 = l4.z & 255, l3 = l4.w & 255;
        atomicAdd(&cnt[l0], 1u); atomicAdd(&cnt[l1], 1u);
        atomicAdd(&cnt[l2], 1u); atomicAdd(&cnt[l3], 1u);
        atomicMin(&sxmin[l0], x);     atomicMax(&sxmax[l0], x);
        atomicMin(&sxmin[l1], x + 1); atomicMax(&sxmax[l1], x + 1);
        atomicMin(&sxmin[l2], x + 2); atomicMax(&sxmax[l2], x + 2);
        atomicMin(&sxmin[l3], x + 3); atomicMax(&sxmax[l3], x + 3);
        atomicMin(&symin[l0], y); atomicMax(&symax[l0], y);
        atomicMin(&symin[l1], y); atomicMax(&symax[l1], y);
        atomicMin(&symin[l2], y); atomicMax(&symax[l2], y);
        atomicMin(&symin[l3], y); atomicMax(&symax[l3], y);
    }
    __syncthreads();
    for (int i = threadIdx.x; i < NSEG; i += blockDim.x) {
        if (cnt[i]) atomicAdd(&rs_out[big * NSEG + i], (float)cnt[i]);
        if (sxmin[i] != INT_MAX) {
            atomicMin(&bb[big * NSEG + i], sxmin[i]);
            atomicMax(&bb[1536 + big * NSEG + i], sxmax[i]);
            atomicMin(&bb[3072 + big * NSEG + i], symin[i]);
            atomicMax(&bb[4608 + big * NSEG + i], symax[i]);
        }
    }
}

// ---- color histogram: per (b,g,c), 6400-bin LDS hist, vectorized ----
__global__ void k_chist(const float* __restrict__ img, const int* __restrict__ lab, float* __restrict__ ch_out) {
    __shared__ unsigned cnt[NSEG * 25];
    int gy = blockIdx.y;       // (b*3+g)*3 + c
    int c = gy % 3;
    int bg = gy / 3;           // b*3+g
    int b = bg / 3;
    for (int i = threadIdx.x; i < NSEG * 25; i += blockDim.x) cnt[i] = 0;
    __syncthreads();
    const float4* ip = (const float4*)(img + ((size_t)b * 3 + c) * HW);
    const int4* lp = (const int4*)(lab + (size_t)bg * HW);
    int stride = blockDim.x * gridDim.x;
    for (int i = blockIdx.x * blockDim.x + threadIdx.x; i < HW / 4; i += stride) {
        float4 v4 = ip[i];
        int4 l4 = lp[i];
        int b0 = (int)((float)(l4.x & 255) * 25.0f + v4.x * 24.0f);
        int b1 = (int)((float)(l4.y & 255) * 25.0f + v4.y * 24.0f);
        int b2 = (int)((float)(l4.z & 255) * 25.0f + v4.z * 24.0f);
        int b3 = (int)((float)(l4.w & 255) * 25.0f + v4.w * 24.0f);
        b0 = min(max(b0, 0), NSEG * 25 - 1); b1 = min(max(b1, 0), NSEG * 25 - 1);
        b2 = min(max(b2, 0), NSEG * 25 - 1); b3 = min(max(b3, 0), NSEG * 25 - 1);
        atomicAdd(&cnt[b0], 1u); atomicAdd(&cnt[b1], 1u);
        atomicAdd(&cnt[b2], 1u); atomicAdd(&cnt[b3], 1u);
    }
    __syncthreads();
    for (int i = threadIdx.x; i < NSEG * 25; i += blockDim.x) {
        unsigned n = cnt[i];
        if (n) {
            int s = i / 25, cb = i - s * 25;
            atomicAdd(&ch_out[((size_t)(bg * NSEG + s) * 3 + c) * 25 + cb], (float)n);
        }
    }
}

// ---- texture histogram: block = (bc,d,base,gi), pos+neg hists together ----
// gy = ((bc*2 + d)*2 + base)*3 + gi ; writes u32 partials (no atomics)
__global__ void k_thist(const float* __restrict__ maps, const int* __restrict__ lab,
                        const float* __restrict__ mm, unsigned* __restrict__ thp) {
    __shared__ unsigned cnt[2 * 2560];  // [0,2560): pos, [2560,5120): neg
    int gy = blockIdx.y;
    int gi = gy % 3;
    int r = gy / 3;
    int base = r & 1;
    int bd = r >> 1;
    int d = bd & 1;
    int bc = bd >> 1;
    int b = bc / 3;
    int m = base * 12 + bc * 2 + d;
    for (int i = threadIdx.x; i < 5120; i += 256) cnt[i] = 0;
    __syncthreads();
    float mn = mm[m * 2], mx = mm[m * 2 + 1];
    float hminp = fmaxf(mn, 0.f);
    float denp = fmaxf(mx, 0.f) - hminp;
    float hminn = fminf(mn, 0.f);
    float denn = fminf(mx, 0.f) - hminn;
    const float4* src = (const float4*)(maps + (size_t)m * HW);
    const int4* lp = (const int4*)(lab + (size_t)(b * 3 + gi) * HW);
    int stride = blockDim.x * gridDim.x;  // 3072
    for (int i = blockIdx.x * blockDim.x + threadIdx.x; i < HW / 4; i += stride) {
        float4 v4 = src[i];
        int4 l4 = lp[i];
#define TH_ONE(V, L)                                                        \
        {                                                                   \
            float v = (V);                                                  \
            float la = (float)((L) & 255);                                  \
            float tp = ((fmaxf(v, 0.f) - hminp) / denp) * 9.0f;             \
            float tn = ((fminf(v, 0.f) - hminn) / denn) * 9.0f;             \
            int bp = (int)(la * 10.0f + tp);                                \
            int bn = (int)(la * 10.0f + tn);                                \
            bp = min(max(bp, 0), 2559);                                     \
            bn = min(max(bn, 0), 2559);                                     \
            atomicAdd(&cnt[bp], 1u);                                        \
            atomicAdd(&cnt[2560 + bn], 1u);                                 \
        }
        TH_ONE(v4.x, l4.x) TH_ONE(v4.y, l4.y) TH_ONE(v4.z, l4.z) TH_ONE(v4.w, l4.w)
#undef TH_ONE
    }
    __syncthreads();
    unsigned* dst = thp + ((size_t)gy * THP + blockIdx.x) * 5120;
    for (int i = threadIdx.x; i < 5120; i += 256) dst[i] = cnt[i];
}

// ---- sum THP partials per (gy,bin) and scatter to th layout (B,I,G,S,C,8,10) ----
__global__ void k_threduce(const unsigned* __restrict__ thp, float* __restrict__ th_out) {
    int gy = blockIdx.x;   // 72
    int gi = gy % 3;
    int r = gy / 3;
    int base = r & 1;
    int bd = r >> 1;
    int d = bd & 1;
    int bc = bd >> 1;
    int b = bc / 3, c = bc - b * 3;
    for (int i = threadIdx.x; i < 5120; i += 256) {
        unsigned s = 0;
        for (int p = 0; p < THP; ++p) s += thp[((size_t)gy * THP + p) * 5120 + i];
        int pos = (i < 2560);
        int rr = pos ? i : i - 2560;
        int seg = rr / 10, tb = rr - seg * 10;
        int t = base * 4 + (pos ? 0 : 2) + d;
        size_t idx = ((size_t)((b * 3 + gi) * NSEG + seg) * 3 + c) * 80 + t * 10 + tb;
        th_out[idx] = (float)s;
    }
}

// ---- normalize ch/th and write xywh ----
__global__ void k_final(float* __restrict__ out, const int* __restrict__ bb) {
    int seg = blockIdx.x;   // big*256 + s, 1536 total
    float rs = out[seg];
    float cd = 3.0f * rs;
    float td = 24.0f * rs;
    float* ch = out + CH_OFF + (size_t)seg * 75;
    float* th = out + TH_OFF + (size_t)seg * 240;
    for (int i = threadIdx.x; i < 75; i += blockDim.x) ch[i] = ch[i] / cd;
    for (int i = threadIdx.x; i < 240; i += blockDim.x) th[i] = th[i] / td;
    if (threadIdx.x == 0) {
        int xmin, xmax, ymin, ymax;
        if (rs > 0.f) {
            xmin = bb[seg]; xmax = bb[1536 + seg];
            ymin = bb[3072 + seg]; ymax = bb[4608 + seg];
        } else {
            xmin = IW; ymin = IW; xmax = 0; ymax = 0;
        }
        float* xy = out + XY_OFF + (size_t)seg * 4;
        xy[0] = (float)xmin; xy[1] = (float)ymin;
        xy[2] = (float)(xmax - xmin); xy[3] = (float)(ymax - ymin);
    }
}

extern "C" void kernel_launch(void* const* d_in, const int* in_sizes, int n_in,
                              void* d_out, int out_size, void* d_ws, size_t ws_size,
                              hipStream_t stream) {
    const float* img = (const float*)d_in[0];
    const int* lab = (const int*)d_in[1];
    float* out = (float*)d_out;

    float* ws = (float*)d_ws;
    float* rot = ws;                              // 6*725*725, padded to ROT_PAD
    float* gmaps = ws + ROT_PAD;                  // 12 maps * 262144 (16B-aligned)
    float* grcmaps = gmaps + (size_t)12 * HW;     // 12 maps (contiguous after g)
    float* pmin = grcmaps + (size_t)12 * HW;      // 24*1024
    float* pmax = pmin + 24 * NBLK;               // 24*1024
    float* mm = pmax + 24 * NBLK;                 // 48 floats
    int* bb = (int*)(mm + 48);                    // 4*1536 ints
    unsigned* thp = (unsigned*)(bb + 4 * 1536);   // 72*THP*5120 u32 (~17.7 MB)

    hipMemsetAsync(d_out, 0, (size_t)out_size * sizeof(float), stream);
    hipLaunchKernelGGL(k_init_bb, dim3(6), dim3(256), 0, stream, bb);
    hipLaunchKernelGGL(k_rot, dim3((RHW + 255) / 256, 6), dim3(256), 0, stream, img, rot);
    hipLaunchKernelGGL(k_scharr_img, dim3(NBLK, 6), dim3(256), 0, stream, img, gmaps, pmin, pmax);
    hipLaunchKernelGGL(k_grc, dim3(NBLK, 6), dim3(256), 0, stream, rot, grcmaps, pmin, pmax);
    hipLaunchKernelGGL(k_mmreduce, dim3(24), dim3(256), 0, stream, pmin, pmax, mm);
    hipLaunchKernelGGL(k_region, dim3(64, 6), dim3(256), 0, stream, lab, out, bb);
    hipLaunchKernelGGL(k_chist, dim3(32, 18), dim3(256), 0, stream, img, lab, out + CH_OFF);
    hipLaunchKernelGGL(k_thist, dim3(THP, 72), dim3(256), 0, stream, gmaps, lab, mm, thp);
    hipLaunchKernelGGL(k_threduce, dim3(72), dim3(256), 0, stream, thp, out + TH_OFF);
    hipLaunchKernelGGL(k_final, dim3(1536), dim3(64), 0, stream, out, bb);
}

// Round 5
// 188.668 us; speedup vs baseline: 3.3161x; 1.1904x over previous
//
#include <hip/hip_runtime.h>
#include <climits>

#define HW 262144          // 512*512
#define IW 512
#define RN 725             // rotated canvas side (virtual now)
#define NSEG 256
#define CH_OFF 1536
#define TH_OFF 116736
#define XY_OFF 485376
#define NBLK 1024          // blocks per image in scharr/grc
#define THP 12             // pixel splits in k_thist

static __device__ __forceinline__ float loadpix(const float* p, int y, int x, int n) {
    return (y >= 0 && y < n && x >= 0 && x < n) ? p[y * n + x] : 0.0f;
}

// virtual rot-canvas sample: canvas coord (cx,cy) -> nearest img pixel (exact k_rot formula)
static __device__ __forceinline__ float rtap(const float* __restrict__ im, int cx, int cy) {
    if (cx < 0 || cx >= RN || cy < 0 || cy >= RN) return 0.f;   // canvas zero-pad
    const float cs = 0.7071067811865476f;
    float xg = (float)cx - 362.0f;          // (725-1)/2
    float yg = (float)cy - 362.0f;
    float xi = cs * xg - cs * yg + 255.5f;  // c*xg - s*yg + (W-1)/2
    float yi = cs * xg + cs * yg + 255.5f;
    int xn = (int)rintf(xi);
    int yn = (int)rintf(yi);
    if (xn < 0 || xn >= IW || yn < 0 || yn >= IW) return 0.f;   // img zero (invalid)
    return im[yn * IW + xn];
}

// block-reduce min/max of (g0,g1); write per-block partials (NO atomics)
static __device__ __forceinline__ void reduce_mm(float g0, float g1, int m0, int m1,
                                                 float* __restrict__ pmin, float* __restrict__ pmax) {
    __shared__ float s0lo[256], s0hi[256], s1lo[256], s1hi[256];
    int tid = threadIdx.x;
    s0lo[tid] = g0; s0hi[tid] = g0; s1lo[tid] = g1; s1hi[tid] = g1;
    __syncthreads();
    for (int off = 128; off > 0; off >>= 1) {
        if (tid < off) {
            s0lo[tid] = fminf(s0lo[tid], s0lo[tid + off]);
            s0hi[tid] = fmaxf(s0hi[tid], s0hi[tid + off]);
            s1lo[tid] = fminf(s1lo[tid], s1lo[tid + off]);
            s1hi[tid] = fmaxf(s1hi[tid], s1hi[tid + off]);
        }
        __syncthreads();
    }
    if (tid == 0) {
        int bx = blockIdx.x;
        pmin[m0 * NBLK + bx] = s0lo[0];
        pmax[m0 * NBLK + bx] = s0hi[0];
        pmin[m1 * NBLK + bx] = s1lo[0];
        pmax[m1 * NBLK + bx] = s1hi[0];
    }
}

// ---- Scharr on 512x512 image + per-block min/max partials ----
__global__ void k_scharr_img(const float* __restrict__ img, float* __restrict__ g,
                             float* __restrict__ pmin, float* __restrict__ pmax) {
    int p = blockIdx.x * blockDim.x + threadIdx.x;
    int bc = blockIdx.y;
    int y = p >> 9, x = p & 511;
    const float* im = img + (size_t)bc * HW;
    float a = loadpix(im, y - 1, x - 1, IW), b = loadpix(im, y - 1, x, IW), c = loadpix(im, y - 1, x + 1, IW);
    float d = loadpix(im, y, x - 1, IW), e = loadpix(im, y, x + 1, IW);
    float f = loadpix(im, y + 1, x - 1, IW), h = loadpix(im, y + 1, x, IW), i = loadpix(im, y + 1, x + 1, IW);
    float g0 = -3.f * a + 3.f * c + 10.f * d + 10.f * e - 3.f * f + 3.f * i;
    float g1 = -3.f * a + 10.f * b - 3.f * c + 3.f * f + 10.f * h + 3.f * i;
    g[((size_t)bc * 2 + 0) * HW + p] = g0;
    g[((size_t)bc * 2 + 1) * HW + p] = g1;
    reduce_mm(g0, g1, bc * 2 + 0, bc * 2 + 1, pmin, pmax);
}

// ---- fused rotate(+45) -> Scharr -> rotate(-45) -> crop, all virtual (no canvas) ----
__global__ void k_grc(const float* __restrict__ img, float* __restrict__ grc,
                      float* __restrict__ pmin, float* __restrict__ pmax) {
    int p = blockIdx.x * blockDim.x + threadIdx.x;
    int bc = blockIdx.y;
    int y = p >> 9, x = p & 511;
    const float cs = 0.7071067811865476f;  // cos(-45); sin(-45) = -cs
    float xg = (float)(x + 105) - 512.5f;  // (1026-1)/2
    float yg = (float)(y + 105) - 512.5f;
    float t1 = cs * xg, t2 = cs * yg;
    float xi = (t1 + t2) + 362.0f;         // back-rotated canvas coord
    float yi = (-t1 + t2) + 362.0f;
    int xn = (int)rintf(xi);
    int yn = (int)rintf(yi);
    float g0 = 0.f, g1 = 0.f;
    if (xn >= 0 && xn < RN && yn >= 0 && yn < RN) {
        const float* im = img + (size_t)bc * HW;
        float a = rtap(im, xn - 1, yn - 1), b = rtap(im, xn, yn - 1), c = rtap(im, xn + 1, yn - 1);
        float d = rtap(im, xn - 1, yn),     e = rtap(im, xn + 1, yn);
        float f = rtap(im, xn - 1, yn + 1), h = rtap(im, xn, yn + 1), i = rtap(im, xn + 1, yn + 1);
        g0 = -3.f * a + 3.f * c + 10.f * d + 10.f * e - 3.f * f + 3.f * i;
        g1 = -3.f * a + 10.f * b - 3.f * c + 3.f * f + 10.f * h + 3.f * i;
    }
    grc[((size_t)bc * 2 + 0) * HW + p] = g0;
    grc[((size_t)bc * 2 + 1) * HW + p] = g1;
    reduce_mm(g0, g1, 12 + bc * 2 + 0, 12 + bc * 2 + 1, pmin, pmax);
}

// ---- stage-2: reduce 1024 partials per map -> mm[m*2], mm[m*2+1] ----
__global__ void k_mmreduce(const float* __restrict__ pmin, const float* __restrict__ pmax,
                           float* __restrict__ mm) {
    int m = blockIdx.x;
    int tid = threadIdx.x;
    float lo = 3.4e38f, hi = -3.4e38f;
    for (int i = tid; i < NBLK; i += 256) {
        lo = fminf(lo, pmin[m * NBLK + i]);
        hi = fmaxf(hi, pmax[m * NBLK + i]);
    }
    __shared__ float slo[256], shi[256];
    slo[tid] = lo; shi[tid] = hi;
    __syncthreads();
    for (int off = 128; off > 0; off >>= 1) {
        if (tid < off) {
            slo[tid] = fminf(slo[tid], slo[tid + off]);
            shi[tid] = fmaxf(shi[tid], shi[tid + off]);
        }
        __syncthreads();
    }
    if (tid == 0) { mm[m * 2] = slo[0]; mm[m * 2 + 1] = shi[0]; }
}

__global__ void k_init_bb(int* __restrict__ bb) {
    int i = blockIdx.x * blockDim.x + threadIdx.x;  // 1536 total
    bb[i] = INT_MAX;            // xmin
    bb[1536 + i] = INT_MIN;     // xmax
    bb[3072 + i] = INT_MAX;     // ymin
    bb[4608 + i] = INT_MIN;     // ymax
}

// ---- region sizes + bbox: LDS hist + LDS min/max, merged with global atomics ----
__global__ void k_region(const int* __restrict__ lab, float* __restrict__ rs_out, int* __restrict__ bb) {
    __shared__ unsigned cnt[NSEG];
    __shared__ int sxmin[NSEG], sxmax[NSEG], symin[NSEG], symax[NSEG];
    int big = blockIdx.y;  // b*3+g
    for (int i = threadIdx.x; i < NSEG; i += blockDim.x) {
        cnt[i] = 0; sxmin[i] = INT_MAX; sxmax[i] = INT_MIN; symin[i] = INT_MAX; symax[i] = INT_MIN;
    }
    __syncthreads();
    const int4* lp = (const int4*)(lab + (size_t)big * HW);
    int stride = blockDim.x * gridDim.x;
    for (int i = blockIdx.x * blockDim.x + threadIdx.x; i < HW / 4; i += stride) {
        int4 l4 = lp[i];
        int p = i << 2;
        int y = p >> 9, x = p & 511;
        int l0 = l4.x & 255, l1 = l4.y & 255, l2 = l4.z & 255, l3 = l4.w & 255;
        atomicAdd(&cnt[l0], 1u); atomicAdd(&cnt[l1], 1u);
        atomicAdd(&cnt[l2], 1u); atomicAdd(&cnt[l3], 1u);
        atomicMin(&sxmin[l0], x);     atomicMax(&sxmax[l0], x);
        atomicMin(&sxmin[l1], x + 1); atomicMax(&sxmax[l1], x + 1);
        atomicMin(&sxmin[l2], x + 2); atomicMax(&sxmax[l2], x + 2);
        atomicMin(&sxmin[l3], x + 3); atomicMax(&sxmax[l3], x + 3);
        atomicMin(&symin[l0], y); atomicMax(&symax[l0], y);
        atomicMin(&symin[l1], y); atomicMax(&symax[l1], y);
        atomicMin(&symin[l2], y); atomicMax(&symax[l2], y);
        atomicMin(&symin[l3], y); atomicMax(&symax[l3], y);
    }
    __syncthreads();
    for (int i = threadIdx.x; i < NSEG; i += blockDim.x) {
        if (cnt[i]) atomicAdd(&rs_out[big * NSEG + i], (float)cnt[i]);
        if (sxmin[i] != INT_MAX) {
            atomicMin(&bb[big * NSEG + i], sxmin[i]);
            atomicMax(&bb[1536 + big * NSEG + i], sxmax[i]);
            atomicMin(&bb[3072 + big * NSEG + i], symin[i]);
            atomicMax(&bb[4608 + big * NSEG + i], symax[i]);
        }
    }
}

// ---- color histogram: per (b,g,c), 6400-bin LDS hist, vectorized ----
__global__ void k_chist(const float* __restrict__ img, const int* __restrict__ lab, float* __restrict__ ch_out) {
    __shared__ unsigned cnt[NSEG * 25];
    int gy = blockIdx.y;       // (b*3+g)*3 + c
    int c = gy % 3;
    int bg = gy / 3;           // b*3+g
    int b = bg / 3;
    for (int i = threadIdx.x; i < NSEG * 25; i += blockDim.x) cnt[i] = 0;
    __syncthreads();
    const float4* ip = (const float4*)(img + ((size_t)b * 3 + c) * HW);
    const int4* lp = (const int4*)(lab + (size_t)bg * HW);
    int stride = blockDim.x * gridDim.x;
    for (int i = blockIdx.x * blockDim.x + threadIdx.x; i < HW / 4; i += stride) {
        float4 v4 = ip[i];
        int4 l4 = lp[i];
        int b0 = (int)((float)(l4.x & 255) * 25.0f + v4.x * 24.0f);
        int b1 = (int)((float)(l4.y & 255) * 25.0f + v4.y * 24.0f);
        int b2 = (int)((float)(l4.z & 255) * 25.0f + v4.z * 24.0f);
        int b3 = (int)((float)(l4.w & 255) * 25.0f + v4.w * 24.0f);
        b0 = min(max(b0, 0), NSEG * 25 - 1); b1 = min(max(b1, 0), NSEG * 25 - 1);
        b2 = min(max(b2, 0), NSEG * 25 - 1); b3 = min(max(b3, 0), NSEG * 25 - 1);
        atomicAdd(&cnt[b0], 1u); atomicAdd(&cnt[b1], 1u);
        atomicAdd(&cnt[b2], 1u); atomicAdd(&cnt[b3], 1u);
    }
    __syncthreads();
    for (int i = threadIdx.x; i < NSEG * 25; i += blockDim.x) {
        unsigned n = cnt[i];
        if (n) {
            int s = i / 25, cb = i - s * 25;
            atomicAdd(&ch_out[((size_t)(bg * NSEG + s) * 3 + c) * 25 + cb], (float)n);
        }
    }
}

// ---- texture histogram: block = (bc,d,base,gi), pos+neg hists together ----
// gy = ((bc*2 + d)*2 + base)*3 + gi ; writes u32 partials (no atomics)
__global__ void k_thist(const float* __restrict__ maps, const int* __restrict__ lab,
                        const float* __restrict__ mm, unsigned* __restrict__ thp) {
    __shared__ unsigned cnt[2 * 2560];  // [0,2560): pos, [2560,5120): neg
    int gy = blockIdx.y;
    int gi = gy % 3;
    int r = gy / 3;
    int base = r & 1;
    int bd = r >> 1;
    int d = bd & 1;
    int bc = bd >> 1;
    int b = bc / 3;
    int m = base * 12 + bc * 2 + d;
    for (int i = threadIdx.x; i < 5120; i += 256) cnt[i] = 0;
    __syncthreads();
    float mn = mm[m * 2], mx = mm[m * 2 + 1];
    float hminp = fmaxf(mn, 0.f);
    float denp = fmaxf(mx, 0.f) - hminp;
    float hminn = fminf(mn, 0.f);
    float denn = fminf(mx, 0.f) - hminn;
    const float4* src = (const float4*)(maps + (size_t)m * HW);
    const int4* lp = (const int4*)(lab + (size_t)(b * 3 + gi) * HW);
    int stride = blockDim.x * gridDim.x;  // 3072
    for (int i = blockIdx.x * blockDim.x + threadIdx.x; i < HW / 4; i += stride) {
        float4 v4 = src[i];
        int4 l4 = lp[i];
#define TH_ONE(V, L)                                                        \
        {                                                                   \
            float v = (V);                                                  \
            float la = (float)((L) & 255);                                  \
            float tp = ((fmaxf(v, 0.f) - hminp) / denp) * 9.0f;             \
            float tn = ((fminf(v, 0.f) - hminn) / denn) * 9.0f;             \
            int bp = (int)(la * 10.0f + tp);                                \
            int bn = (int)(la * 10.0f + tn);                                \
            bp = min(max(bp, 0), 2559);                                     \
            bn = min(max(bn, 0), 2559);                                     \
            atomicAdd(&cnt[bp], 1u);                                        \
            atomicAdd(&cnt[2560 + bn], 1u);                                 \
        }
        TH_ONE(v4.x, l4.x) TH_ONE(v4.y, l4.y) TH_ONE(v4.z, l4.z) TH_ONE(v4.w, l4.w)
#undef TH_ONE
    }
    __syncthreads();
    unsigned* dst = thp + ((size_t)gy * THP + blockIdx.x) * 5120;
    for (int i = threadIdx.x; i < 5120; i += 256) dst[i] = cnt[i];
}

// ---- sum THP partials per (gy,bin) and scatter to th layout (B,I,G,S,C,8,10) ----
__global__ void k_threduce(const unsigned* __restrict__ thp, float* __restrict__ th_out) {
    int gy = blockIdx.x;   // 72
    int gi = gy % 3;
    int r = gy / 3;
    int base = r & 1;
    int bd = r >> 1;
    int d = bd & 1;
    int bc = bd >> 1;
    int b = bc / 3, c = bc - b * 3;
    for (int i = threadIdx.x; i < 5120; i += 256) {
        unsigned s = 0;
        for (int p = 0; p < THP; ++p) s += thp[((size_t)gy * THP + p) * 5120 + i];
        int pos = (i < 2560);
        int rr = pos ? i : i - 2560;
        int seg = rr / 10, tb = rr - seg * 10;
        int t = base * 4 + (pos ? 0 : 2) + d;
        size_t idx = ((size_t)((b * 3 + gi) * NSEG + seg) * 3 + c) * 80 + t * 10 + tb;
        th_out[idx] = (float)s;
    }
}

// ---- normalize ch/th and write xywh ----
__global__ void k_final(float* __restrict__ out, const int* __restrict__ bb) {
    int seg = blockIdx.x;   // big*256 + s, 1536 total
    float rs = out[seg];
    float cd = 3.0f * rs;
    float td = 24.0f * rs;
    float* ch = out + CH_OFF + (size_t)seg * 75;
    float* th = out + TH_OFF + (size_t)seg * 240;
    for (int i = threadIdx.x; i < 75; i += blockDim.x) ch[i] = ch[i] / cd;
    for (int i = threadIdx.x; i < 240; i += blockDim.x) th[i] = th[i] / td;
    if (threadIdx.x == 0) {
        int xmin, xmax, ymin, ymax;
        if (rs > 0.f) {
            xmin = bb[seg]; xmax = bb[1536 + seg];
            ymin = bb[3072 + seg]; ymax = bb[4608 + seg];
        } else {
            xmin = IW; ymin = IW; xmax = 0; ymax = 0;
        }
        float* xy = out + XY_OFF + (size_t)seg * 4;
        xy[0] = (float)xmin; xy[1] = (float)ymin;
        xy[2] = (float)(xmax - xmin); xy[3] = (float)(ymax - ymin);
    }
}

extern "C" void kernel_launch(void* const* d_in, const int* in_sizes, int n_in,
                              void* d_out, int out_size, void* d_ws, size_t ws_size,
                              hipStream_t stream) {
    const float* img = (const float*)d_in[0];
    const int* lab = (const int*)d_in[1];
    float* out = (float*)d_out;

    float* ws = (float*)d_ws;
    float* gmaps = ws;                            // 12 maps * 262144
    float* grcmaps = gmaps + (size_t)12 * HW;     // 12 maps (contiguous after g)
    float* pmin = grcmaps + (size_t)12 * HW;      // 24*1024
    float* pmax = pmin + 24 * NBLK;               // 24*1024
    float* mm = pmax + 24 * NBLK;                 // 48 floats
    int* bb = (int*)(mm + 48);                    // 4*1536 ints
    unsigned* thp = (unsigned*)(bb + 4 * 1536);   // 72*THP*5120 u32 (~17.7 MB)

    hipMemsetAsync(d_out, 0, (size_t)out_size * sizeof(float), stream);
    hipLaunchKernelGGL(k_init_bb, dim3(6), dim3(256), 0, stream, bb);
    hipLaunchKernelGGL(k_scharr_img, dim3(NBLK, 6), dim3(256), 0, stream, img, gmaps, pmin, pmax);
    hipLaunchKernelGGL(k_grc, dim3(NBLK, 6), dim3(256), 0, stream, img, grcmaps, pmin, pmax);
    hipLaunchKernelGGL(k_mmreduce, dim3(24), dim3(256), 0, stream, pmin, pmax, mm);
    hipLaunchKernelGGL(k_region, dim3(64, 6), dim3(256), 0, stream, lab, out, bb);
    hipLaunchKernelGGL(k_chist, dim3(32, 18), dim3(256), 0, stream, img, lab, out + CH_OFF);
    hipLaunchKernelGGL(k_thist, dim3(THP, 72), dim3(256), 0, stream, gmaps, lab, mm, thp);
    hipLaunchKernelGGL(k_threduce, dim3(72), dim3(256), 0, stream, thp, out + TH_OFF);
    hipLaunchKernelGGL(k_final, dim3(1536), dim3(64), 0, stream, out, bb);
}